// Round 12
// baseline (350.737 us; speedup 1.0000x reference)
//
#include <hip/hip_runtime.h>
#include <hip/hip_bf16.h>

// CorrelationLayerCosineSimilarity via banded bf16 MFMA GEMM.
// out[b,d,h,w] = dot_c(x1,x2p shifted d) / max(n1*n2, 1e-6); B=4,C=256,H=128,W=256,D=41.
//
// Round 12: 32 OUTSTANDING BATCHES PER CU (16 waves x 2-deep), spill-free.
//  - Model (R4/R6/R9/R11): perf tracks outstanding load batches/CU.
//    R6 = 16x1 = 16 -> 58us; R9 = 8x2 = 16 -> 63us (same). Untested: 32.
//  - W-split grid 1024 (b, h, w-half) x 512 thr (8 waves). Wave v owns ONE
//    w-tile (acc 16 regs) and stages 4 channels/K-step (24 regs/set).
//    2 named-scalar sets + acc + addr + ssq ~ 110 regs < 128 cap of
//    __launch_bounds__(512,4) -> 2 blocks/CU, 16 waves/CU, NO SPILLS
//    (R11 spilled: 256-thr waves needed ~130 > 128).
//  - 2-deep ping-pong (R8 macros) + raw-barrier PHASE_BAR (R6): loads for
//    ks+2 issued at pack(ks), consumed at pack(ks+2) -> ~2 full iterations
//    of latency cover, vmem stays in flight across all barriers.
//
// LDS: A[wl 0..127][kc 0..31] bf16 rows of 80B (4x16B slots + pad slot;
// logical slot s of row r at physical (s+r)%5 -> conflict-free b128 frag
// reads). B[wl' 0..175][kc] same; rows 168..175 never written (feed only
// discarded cols; epilogue reads Sw col mm+d <= 55). Epilogue scratch
// 8 x 4224B overlays staging; norms (296 f32) live PAST it at 33792.

#define B_   4
#define C_   256
#define H_   128
#define W_   256
#define ND_  41
#define HW_  (H_ * W_)
#define CHW_ (C_ * HW_)
#define EPS_ 1e-6f

typedef __attribute__((ext_vector_type(4))) float f32x4;
typedef __attribute__((ext_vector_type(8))) short bf16x8;

#define ABASE 0
#define BBASE 10240            // A: 128*80
#define NBASE 33792            // past epilogue scratch 8*4224
#define LDSZ  34976            // NBASE + 296*4

// Phase boundary: own-lgkm drain + raw barrier, vmem loads stay in flight.
#define PHASE_BAR() do {                                         \
    __builtin_amdgcn_sched_barrier(0);                           \
    asm volatile("s_waitcnt lgkmcnt(0)" ::: "memory");           \
    __builtin_amdgcn_s_barrier();                                \
    __builtin_amdgcn_sched_barrier(0);                           \
  } while (0)

__device__ __forceinline__ unsigned bfr(float x) {   // fp32 -> bf16 bits, RNE
  unsigned u = __builtin_bit_cast(unsigned, x);
  return (u + 0x7fffu + ((u >> 16) & 1u)) >> 16;
}

__global__ __launch_bounds__(512, 4)
void corr_mfma(const float* __restrict__ x1, const float* __restrict__ x2,
               float* __restrict__ out) {
  __shared__ __align__(16) char lds[LDSZ];

  const int tid = threadIdx.x;
  const int l   = tid & 63;
  const int v   = tid >> 6;          // wave id, 0..7
  const int m   = l & 15;
  const int g   = l >> 4;
  const int q   = l & 31;            // staging w-quad
  const int h2  = l >> 5;            // staging channel-pair half

  const int r    = blockIdx.x;
  const int half = r & 1;
  const int hh   = (r >> 1) & (H_ - 1);
  const int b    = r >> 8;
  const int wb   = 128 * half;       // block's w origin

  const float* X1 = x1 + b * CHW_ + hh * W_ + wb;
  const float* X2 = x2 + b * CHW_ + hh * W_ + wb;

  // ---- prologue: zero norm accumulators (512 thr >= 296) ----
  if (tid < 296) ((float*)(lds + NBASE))[tid] = 0.f;

  // ---- loop-invariant addresses ----
  // wave v stages channels kc = 4v + 2*h2 + {0,1}: one 4B write per row.
  int wadrA[4], wadrBb[4];
#pragma unroll
  for (int jj = 0; jj < 4; ++jj) {
    int wa = 4 * q + jj;
    wadrA[jj] = ABASE + wa * 80 + (((v >> 1) + wa) % 5) * 16
              + 8 * (v & 1) + 4 * h2;
    int wbb = 128 + 4 * q + jj;
    wadrBb[jj] = BBASE + wbb * 80 + (((v >> 1) + wbb) % 5) * 16
               + 8 * (v & 1) + 4 * h2;
  }
  const int rowA = 16 * v + m;
  const int adrA = ABASE + rowA * 80 + ((g + rowA) % 5) * 16;
  int adrB[4];
#pragma unroll
  for (int c = 0; c < 4; ++c) {
    int col = 16 * (v + c) + m;       // <= 175
    adrB[c] = BBASE + col * 80 + ((g + col) % 5) * 16;
  }

  f32x4 acc[4];
#pragma unroll
  for (int c = 0; c < 4; ++c) acc[c] = (f32x4){0.f, 0.f, 0.f, 0.f};
  float ssq1[4]  = {0.f, 0.f, 0.f, 0.f};
  float ssq2a[4] = {0.f, 0.f, 0.f, 0.f};
  float ssq2b[4] = {0.f, 0.f, 0.f, 0.f};

  const bool ldb = (q < 10) && (half == 0);   // x2 overlap real-load predicate
  const f32x4 z4 = (f32x4){0.f, 0.f, 0.f, 0.f};

  // ---- dual register sets as NAMED scalars (spill-proof, R8 style) ----
  f32x4 r1A0, r1A1, r2aA0, r2aA1, r2bA0, r2bA1;
  f32x4 r1B0, r1B1, r2aB0, r2aB1, r2bB0, r2bB1;

#define LOADSET(S, ks_) do {                                                \
    const float* _p1 = X1 + ((ks_) * 32 + 4 * v + 2 * h2) * HW_ + 4 * q;    \
    const float* _p2 = X2 + ((ks_) * 32 + 4 * v + 2 * h2) * HW_ + 4 * q;    \
    r1##S##0  = *(const f32x4*)(_p1);                                       \
    r1##S##1  = *(const f32x4*)(_p1 + HW_);                                 \
    r2a##S##0 = *(const f32x4*)(_p2);                                       \
    r2a##S##1 = *(const f32x4*)(_p2 + HW_);                                 \
    r2b##S##0 = ldb ? *(const f32x4*)(_p2 + 128) : z4;                      \
    r2b##S##1 = ldb ? *(const f32x4*)(_p2 + HW_ + 128) : z4;                \
  } while (0)

#define PACK(S) do {                                                        \
    _Pragma("unroll")                                                       \
    for (int jj = 0; jj < 4; ++jj) {                                        \
      ssq1[jj]  += r1##S##0[jj] * r1##S##0[jj] + r1##S##1[jj] * r1##S##1[jj];   \
      ssq2a[jj] += r2a##S##0[jj] * r2a##S##0[jj] + r2a##S##1[jj] * r2a##S##1[jj]; \
      ssq2b[jj] += r2b##S##0[jj] * r2b##S##0[jj] + r2b##S##1[jj] * r2b##S##1[jj]; \
      unsigned u1 = bfr(r1##S##0[jj]) | (bfr(r1##S##1[jj]) << 16);          \
      unsigned u2 = bfr(r2a##S##0[jj]) | (bfr(r2a##S##1[jj]) << 16);        \
      *(unsigned*)(lds + wadrA[jj]) = u1;                                   \
      *(unsigned*)(lds + wadrA[jj] + BBASE) = u2;                           \
      if (q < 10) {                   /* zeros when half==1 (pad cols) */   \
        unsigned u3 = bfr(r2b##S##0[jj]) | (bfr(r2b##S##1[jj]) << 16);      \
        *(unsigned*)(lds + wadrBb[jj]) = u3;                                \
      }                                                                     \
    }                                                                       \
  } while (0)

#define MFMA_STEP() do {                                                    \
    bf16x8 a0 = *(const bf16x8*)(lds + adrA);                               \
    _Pragma("unroll")                                                       \
    for (int c = 0; c < 4; ++c) {                                           \
      bf16x8 b0 = *(const bf16x8*)(lds + adrB[c]);                          \
      acc[c] = __builtin_amdgcn_mfma_f32_16x16x32_bf16(a0, b0, acc[c], 0, 0, 0); \
    }                                                                       \
  } while (0)

#define BODY(S, ks_) do {                                                   \
    PHASE_BAR();                      /* B1: prev tile's frag reads done */ \
    PACK(S);                          /* consume set S = data of ks */      \
    if ((ks_) < 6) LOADSET(S, (ks_) + 2);  /* refill; in flight across */   \
    PHASE_BAR();                      /* B2: tile ready */                  \
    MFMA_STEP();                                                            \
  } while (0)

  LOADSET(A, 0);
  LOADSET(B, 1);

  BODY(A, 0); BODY(B, 1);
  BODY(A, 2); BODY(B, 3);
  BODY(A, 4); BODY(B, 5);
  BODY(A, 6); BODY(B, 7);

  // ---- norms: LDS atomic reduce, then sqrt in place ----
  float* nsq = (float*)(lds + NBASE);   // n1sq[128] | n2sq[168]
#pragma unroll
  for (int jj = 0; jj < 4; ++jj) {
    atomicAdd(nsq + 4 * q + jj, ssq1[jj]);
    atomicAdd(nsq + 128 + 4 * q + jj, ssq2a[jj]);
    if (q < 10) atomicAdd(nsq + 256 + 4 * q + jj, ssq2b[jj]);
  }
  __syncthreads();                    // all frag reads of A/B also done
  if (tid < 296) nsq[tid] = sqrtf(nsq[tid]);
  __syncthreads();

  // ---- epilogue: per-wave transpose -> normalize -> coalesced stores ----
  float* Sw  = (float*)(lds + v * 4224);   // 16 x 66 f32, overlays staging
  float* n1s = nsq;                        // [128] local w
  float* n2s = nsq + 128;                  // [168] local w'
#pragma unroll
  for (int c = 0; c < 4; ++c)
#pragma unroll
    for (int rr = 0; rr < 4; ++rr)
      Sw[(4 * g + rr) * 66 + 16 * c + m] = acc[c][rr];
  // wave-internal LDS RAW: in-order per wave + compiler lgkm waits
  const int wq = l & 3, dd = l >> 2;
  const int w0 = 16 * v + 4 * wq;          // local w
#pragma unroll
  for (int p = 0; p < 3; ++p) {
    int d = 16 * p + dd;                   // 0..47
    if (d <= 40) {
      f32x4 o;
#pragma unroll
      for (int j = 0; j < 4; ++j) {
        int mm = 4 * wq + j;               // w within tile
        float dot = Sw[mm * 66 + mm + d];  // col = w-in-tile + d
        o[j] = dot / fmaxf(n1s[w0 + j] * n2s[w0 + j + d], EPS_);
      }
      *(f32x4*)(out + ((b * ND_ + d) * H_ + hh) * W_ + wb + w0) = o;
    }
  }
}

extern "C" void kernel_launch(void* const* d_in, const int* in_sizes, int n_in,
                              void* d_out, int out_size, void* d_ws, size_t ws_size,
                              hipStream_t stream) {
  const float* x1 = (const float*)d_in[0];
  const float* x2 = (const float*)d_in[1];
  float* out = (float*)d_out;
  dim3 grid(B_ * H_ * 2);
  dim3 block(512);
  hipLaunchKernelGGL(corr_mfma, grid, block, 0, stream, x1, x2, out);
}

// Round 13
// 135.255 us; speedup vs baseline: 2.5932x; 2.5932x over previous
//
#include <hip/hip_runtime.h>
#include <hip/hip_bf16.h>

// CorrelationLayerCosineSimilarity via banded bf16 MFMA GEMM.
// out[b,d,h,w] = dot_c(x1,x2p shifted d) / max(n1*n2, 1e-6); B=4,C=256,H=128,W=256,D=41.
//
// Round 13: R12 (W-split, 512 thr, 2-deep ping-pong — indexing verified
// correct) with ALL HOT-LOOP DIVERGENCE REMOVED. R11/R12 spilled (VGPR 64,
// SGPR 32, FETCH/WRITE inflated) because the per-lane-predicated overlap
// load (`ldb ? load : z4`, ldb = f(lane)) forced exec-masked addressing and
// killed SGPR base hoisting. Changes:
//  - x2 overlap loads are UNCONDITIONAL all-lane loads (cols 128+4q <= 255,
//    always in-bounds). For half==1 the pointer is WAVE-UNIFORMLY redirected
//    to the r2a range (L1 hits); values zeroed ARITHMETICALLY via mulB (1/0,
//    wave-uniform SGPR) before ssq and packing — pad cols stage exact zeros.
//  - B LDS region extended to 256 rows: all 32 lane-quads write x2B rows
//    128+4q unconditionally. Rows >= 168 feed only discarded d>40 output
//    columns (MFMA output col depends only on B col — no contamination).
//  - Only divergence left: `q<10` gate on 3 epilogue atomics.
// Structure: 2-deep named-scalar ping-pong (loads for ks+2 issued at
// pack(ks)), raw-barrier PHASE_BAR (no vmcnt drain across barriers),
// __launch_bounds__(512,4) -> 2 blocks/CU, 16 waves/CU, 32 batches in flight.
//
// LDS: A[wl 0..127][kc 0..31] bf16 rows of 80B (4x16B slots + pad slot;
// logical slot s of row r at physical (s+r)%5 -> conflict-free b128 frag
// reads). B[wl' 0..255][kc] same. Epilogue scratch 8x4224B overlays staging;
// norms (296 f32) at 33792.

#define B_   4
#define C_   256
#define H_   128
#define W_   256
#define ND_  41
#define HW_  (H_ * W_)
#define CHW_ (C_ * HW_)
#define EPS_ 1e-6f

typedef __attribute__((ext_vector_type(4))) float f32x4;
typedef __attribute__((ext_vector_type(8))) short bf16x8;

#define ABASE 0
#define BBASE 10240            // A: 128*80
#define NBASE 33792            // past epilogue scratch 8*4224 (B ends 30720)
#define LDSZ  34976            // NBASE + 296*4

// Phase boundary: own-lgkm drain + raw barrier, vmem loads stay in flight.
#define PHASE_BAR() do {                                         \
    __builtin_amdgcn_sched_barrier(0);                           \
    asm volatile("s_waitcnt lgkmcnt(0)" ::: "memory");           \
    __builtin_amdgcn_s_barrier();                                \
    __builtin_amdgcn_sched_barrier(0);                           \
  } while (0)

__device__ __forceinline__ unsigned bfr(float x) {   // fp32 -> bf16 bits, RNE
  unsigned u = __builtin_bit_cast(unsigned, x);
  return (u + 0x7fffu + ((u >> 16) & 1u)) >> 16;
}

__global__ __launch_bounds__(512, 4)
void corr_mfma(const float* __restrict__ x1, const float* __restrict__ x2,
               float* __restrict__ out) {
  __shared__ __align__(16) char lds[LDSZ];

  const int tid = threadIdx.x;
  const int l   = tid & 63;
  const int v   = tid >> 6;          // wave id, 0..7
  const int m   = l & 15;
  const int g   = l >> 4;
  const int q   = l & 31;            // staging w-quad
  const int h2  = l >> 5;            // staging channel-pair half

  const int r    = blockIdx.x;
  const int half = r & 1;
  const int hh   = (r >> 1) & (H_ - 1);
  const int b    = r >> 8;
  const int wb   = 128 * half;       // block's w origin

  const float* X1 = x1 + b * CHW_ + hh * W_ + wb;
  const float* X2 = x2 + b * CHW_ + hh * W_ + wb;
  const int   ofsB = (half == 0) ? 128 : 0;      // wave-uniform overlap offset
  const float mulB = (half == 0) ? 1.f : 0.f;    // wave-uniform pad zeroing

  // ---- prologue: zero norm accumulators ----
  if (tid < 296) ((float*)(lds + NBASE))[tid] = 0.f;

  // ---- loop-invariant addresses ----
  // wave v stages channels kc = 4v + 2*h2 + {0,1}: one 4B write per row.
  int wadrA[4], wadrBb[4];
#pragma unroll
  for (int jj = 0; jj < 4; ++jj) {
    int wa = 4 * q + jj;
    wadrA[jj] = ABASE + wa * 80 + (((v >> 1) + wa) % 5) * 16
              + 8 * (v & 1) + 4 * h2;
    int wbb = 128 + 4 * q + jj;                  // 128..255
    wadrBb[jj] = BBASE + wbb * 80 + (((v >> 1) + wbb) % 5) * 16
               + 8 * (v & 1) + 4 * h2;
  }
  const int rowA = 16 * v + m;
  const int adrA = ABASE + rowA * 80 + ((g + rowA) % 5) * 16;
  int adrB[4];
#pragma unroll
  for (int c = 0; c < 4; ++c) {
    int col = 16 * (v + c) + m;       // <= 175
    adrB[c] = BBASE + col * 80 + ((g + col) % 5) * 16;
  }

  f32x4 acc[4];
#pragma unroll
  for (int c = 0; c < 4; ++c) acc[c] = (f32x4){0.f, 0.f, 0.f, 0.f};
  float ssq1[4]  = {0.f, 0.f, 0.f, 0.f};
  float ssq2a[4] = {0.f, 0.f, 0.f, 0.f};
  float ssq2b[4] = {0.f, 0.f, 0.f, 0.f};

  // ---- dual register sets as NAMED scalars ----
  f32x4 r1A0, r1A1, r2aA0, r2aA1, r2bA0, r2bA1;
  f32x4 r1B0, r1B1, r2aB0, r2aB1, r2bB0, r2bB1;

#define LOADSET(S, ks_) do {                                                \
    const float* _p1 = X1 + ((ks_) * 32 + 4 * v + 2 * h2) * HW_ + 4 * q;    \
    const float* _p2 = X2 + ((ks_) * 32 + 4 * v + 2 * h2) * HW_ + 4 * q;    \
    r1##S##0  = *(const f32x4*)(_p1);                                       \
    r1##S##1  = *(const f32x4*)(_p1 + HW_);                                 \
    r2a##S##0 = *(const f32x4*)(_p2);                                       \
    r2a##S##1 = *(const f32x4*)(_p2 + HW_);                                 \
    r2b##S##0 = *(const f32x4*)(_p2 + ofsB);                                \
    r2b##S##1 = *(const f32x4*)(_p2 + HW_ + ofsB);                          \
  } while (0)

#define PACK(S) do {                                                        \
    _Pragma("unroll")                                                       \
    for (int jj = 0; jj < 4; ++jj) {                                        \
      float sb0 = r2b##S##0[jj] * mulB, sb1 = r2b##S##1[jj] * mulB;         \
      ssq1[jj]  += r1##S##0[jj] * r1##S##0[jj] + r1##S##1[jj] * r1##S##1[jj];     \
      ssq2a[jj] += r2a##S##0[jj] * r2a##S##0[jj] + r2a##S##1[jj] * r2a##S##1[jj]; \
      ssq2b[jj] += sb0 * sb0 + sb1 * sb1;                                   \
      unsigned u1 = bfr(r1##S##0[jj]) | (bfr(r1##S##1[jj]) << 16);          \
      unsigned u2 = bfr(r2a##S##0[jj]) | (bfr(r2a##S##1[jj]) << 16);        \
      unsigned u3 = bfr(sb0) | (bfr(sb1) << 16);                            \
      *(unsigned*)(lds + wadrA[jj]) = u1;                                   \
      *(unsigned*)(lds + wadrA[jj] + BBASE) = u2;                           \
      *(unsigned*)(lds + wadrBb[jj]) = u3;                                  \
    }                                                                       \
  } while (0)

#define MFMA_STEP() do {                                                    \
    bf16x8 a0 = *(const bf16x8*)(lds + adrA);                               \
    _Pragma("unroll")                                                       \
    for (int c = 0; c < 4; ++c) {                                           \
      bf16x8 b0 = *(const bf16x8*)(lds + adrB[c]);                          \
      acc[c] = __builtin_amdgcn_mfma_f32_16x16x32_bf16(a0, b0, acc[c], 0, 0, 0); \
    }                                                                       \
  } while (0)

#define BODY(S, ks_) do {                                                   \
    PHASE_BAR();                      /* B1: prev tile's frag reads done */ \
    PACK(S);                          /* consume set S = data of ks */      \
    if ((ks_) < 6) LOADSET(S, (ks_) + 2);  /* refill; in flight across */   \
    PHASE_BAR();                      /* B2: tile ready */                  \
    MFMA_STEP();                                                            \
  } while (0)

  LOADSET(A, 0);
  LOADSET(B, 1);

  BODY(A, 0); BODY(B, 1);
  BODY(A, 2); BODY(B, 3);
  BODY(A, 4); BODY(B, 5);
  BODY(A, 6); BODY(B, 7);

  // ---- norms: LDS atomic reduce, then sqrt in place ----
  float* nsq = (float*)(lds + NBASE);   // n1sq[128] | n2sq[168]
#pragma unroll
  for (int jj = 0; jj < 4; ++jj) {
    atomicAdd(nsq + 4 * q + jj, ssq1[jj]);
    atomicAdd(nsq + 128 + 4 * q + jj, ssq2a[jj]);
    if (q < 10) atomicAdd(nsq + 256 + 4 * q + jj, ssq2b[jj]);
  }
  __syncthreads();                    // all frag reads of A/B also done
  if (tid < 296) nsq[tid] = sqrtf(nsq[tid]);
  __syncthreads();

  // ---- epilogue: per-wave transpose -> normalize -> coalesced stores ----
  float* Sw  = (float*)(lds + v * 4224);   // 16 x 66 f32, overlays staging
  float* n1s = nsq;                        // [128] local w
  float* n2s = nsq + 128;                  // [168] local w'
#pragma unroll
  for (int c = 0; c < 4; ++c)
#pragma unroll
    for (int rr = 0; rr < 4; ++rr)
      Sw[(4 * g + rr) * 66 + 16 * c + m] = acc[c][rr];
  // wave-internal LDS RAW: in-order per wave + compiler lgkm waits
  const int wq = l & 3, dd = l >> 2;
  const int w0 = 16 * v + 4 * wq;          // local w
#pragma unroll
  for (int p = 0; p < 3; ++p) {
    int d = 16 * p + dd;                   // 0..47
    if (d <= 40) {
      f32x4 o;
#pragma unroll
      for (int j = 0; j < 4; ++j) {
        int mm = 4 * wq + j;               // w within tile
        float dot = Sw[mm * 66 + mm + d];  // col = w-in-tile + d
        o[j] = dot / fmaxf(n1s[w0 + j] * n2s[w0 + j + d], EPS_);
      }
      *(f32x4*)(out + ((b * ND_ + d) * H_ + hh) * W_ + wb + w0) = o;
    }
  }
}

extern "C" void kernel_launch(void* const* d_in, const int* in_sizes, int n_in,
                              void* d_out, int out_size, void* d_ws, size_t ws_size,
                              hipStream_t stream) {
  const float* x1 = (const float*)d_in[0];
  const float* x2 = (const float*)d_in[1];
  float* out = (float*)d_out;
  dim3 grid(B_ * H_ * 2);
  dim3 block(512);
  hipLaunchKernelGGL(corr_mfma, grid, block, 0, stream, x1, x2, out);
}